// Round 15
// baseline (279.038 us; speedup 1.0000x reference)
//
#include <hip/hip_runtime.h>
#include <hip/hip_bf16.h>

// DigitCaps dynamic routing. Output fp32.
// R28: DIAGNOSTIC #2 (decisive). R26 chain with EVERY phase duplicated:
// prep x2, sgemm x2/iter (R27: 3x(S+b)=57.5us), agg2 shadowed x2 into
// scratch (bijT2/Bs2/esum2; real state untouched; ctrA self-resets so
// sharing is safe). Readings:
//   T - 229.3 = (prep+b) + 2(A+b)           [direct split]
//   T ~ 343.6 + b - C0                      [C0 = fixed per-launch overhead]
// T~345-360 -> C0~0, keep optimizing kernels; T~295-315 -> C0~40 (fixed
// harness cost), floor ~155, polish then stop.
// Kernel bodies byte-identical to R26 (171.8us champion).
#define B 512
#define IC 1152
#define QD 8
#define OD 10
#define PD 16
#define KD (IC * QD)       // 9216
#define NKB (KD / 32)      // 288 K32 blocks
#define NCS 12             // K-chunks for s GEMM; grid 32*12 = 384 blocks
#define KSTEPS 6           // 288 / (NCS*4 waves)
#define MB 32              // M-tiles (16 rows each)
#define NCB 4              // b-chunks for agreement GEMM (128 each)
#define SOP (B * OD * PD)  // 81920
#define IO (IC * OD)       // 11520
#define TPX ((B / 64) * (KD / 64))  // 8*144 = 1152 transpose tiles

typedef short bf16x8 __attribute__((ext_vector_type(8)));
typedef short bf16x4 __attribute__((ext_vector_type(4)));
typedef float f32x4 __attribute__((ext_vector_type(4)));

__device__ __forceinline__ short f2bf(float f) {
  union { float f; unsigned u; } x;
  x.f = f;
  unsigned r = x.u + 0x7FFFu + ((x.u >> 16) & 1u);  // RNE to bf16
  return (short)(r >> 16);
}

// ---------------- prep: xB + xT transpose, Bs = bf16(W), zero state ---------
__global__ __launch_bounds__(256) void prep_kernel(const float* __restrict__ x,
                                                   const float* __restrict__ W,
                                                   float* __restrict__ bijT,
                                                   int* __restrict__ ctrS,
                                                   int* __restrict__ ctrA,
                                                   float* __restrict__ esum,
                                                   short* __restrict__ Bs,
                                                   short* __restrict__ xB,
                                                   short* __restrict__ xT) {
  const int bid = blockIdx.x, tid = threadIdx.x;
  // distributed state zeroing
  {
    const int g = bid * 256 + tid;
    if (g < IO) bijT[g] = 0.f;
    const int z = g - IO;
    if (z >= 0) {
      if (z < 32) ctrS[z] = 0;
      else if (z < 192) ctrA[z - 32] = 0;
      else if (z < 240) esum[z - 192] = (z - 192 < 16) ? (float)IC : 0.f;
    }
  }
  if (bid < TPX) {
    // 64 b x 64 iq tile: read x fp32, emit xB (linear bf16) + xT (transposed)
    __shared__ short lds[64 * 72];  // [iq_loc][b_loc], pad 72
    const int bt = bid / (KD / 64), qt = bid % (KD / 64);
    const int b0 = bt * 64, c0 = qt * 64;
    const int row0 = tid >> 4, col4 = (tid & 15) * 4;
#pragma unroll
    for (int j = 0; j < 4; ++j) {
      const int row = row0 + j * 16;
      const float4 v = *(const float4*)(x + (size_t)(b0 + row) * KD + c0 + col4);
      bf16x4 ov;
      ov[0] = f2bf(v.x); ov[1] = f2bf(v.y); ov[2] = f2bf(v.z); ov[3] = f2bf(v.w);
      *(bf16x4*)(xB + (size_t)(b0 + row) * KD + c0 + col4) = ov;
      lds[(col4 + 0) * 72 + row] = ov[0];
      lds[(col4 + 1) * 72 + row] = ov[1];
      lds[(col4 + 2) * 72 + row] = ov[2];
      lds[(col4 + 3) * 72 + row] = ov[3];
    }
    __syncthreads();
    const int iq = tid & 63, seg = tid >> 6;  // 16 b per (iq,seg)
    const short* src = lds + iq * 72 + seg * 16;
    short* dst = xT + (size_t)(c0 + iq) * B + b0 + seg * 16;
    *(bf16x8*)dst = *(const bf16x8*)src;
    *(bf16x8*)(dst + 8) = *(const bf16x8*)(src + 8);
    return;
  }
  const int t = (bid - TPX) * 256 + tid;  // 0..46079
  const int kb = t / 160, n = t % 160;
  const int o = n >> 4, p = n & 15;
  short ov[32];
#pragma unroll
  for (int quad = 0; quad < 4; ++quad) {
    const int i = kb * 4 + quad;
    const float4* wp = (const float4*)(W + (((size_t)i * OD + o) * PD + p) * QD);
    const float4 w0 = wp[0], w1 = wp[1];
    ov[quad * 8 + 0] = f2bf(w0.x); ov[quad * 8 + 1] = f2bf(w0.y);
    ov[quad * 8 + 2] = f2bf(w0.z); ov[quad * 8 + 3] = f2bf(w0.w);
    ov[quad * 8 + 4] = f2bf(w1.x); ov[quad * 8 + 5] = f2bf(w1.y);
    ov[quad * 8 + 6] = f2bf(w1.z); ov[quad * 8 + 7] = f2bf(w1.w);
  }
  int4* dst = (int4*)(Bs + (size_t)t * 32);
  const int4* src = (const int4*)ov;
#pragma unroll
  for (int j = 0; j < 4; ++j) dst[j] = src[j];
}

// ---------------- sgemm: 16-row tile, 4-wave K-split, coalesced WT stores ---
// grid MB*NCS; mb = bid&31 (co-XCD per mb), cz = bid>>5. Finisher = last cz.
__global__ __launch_bounds__(256) void sgemm_kernel(const short* __restrict__ xB,
                                                    const short* __restrict__ Bs,
                                                    const float* __restrict__ esum_in,
                                                    float* __restrict__ s_part,
                                                    int* __restrict__ ctrS,
                                                    short* __restrict__ vB,
                                                    float* __restrict__ out,
                                                    int write_out) {
  __shared__ float sbuf[4][16][168];  // 43KB, +8 pad
  __shared__ int flag;
  __shared__ float einv[OD];
  const int tid = threadIdx.x;
  const int wave = tid >> 6, lane = tid & 63;
  const int ln = lane & 15, quad = lane >> 4;
  const int mb = blockIdx.x & 31, cz = blockIdx.x >> 5;  // co-XCD swizzle
  const int m0 = mb * 16;
  const int czw = cz * 4 + wave;  // 0..47 K-chunks of 6 K32-steps
  f32x4 acc[10] = {};
  const short* arow = xB + (size_t)(m0 + ln) * KD + quad * 8;
#pragma unroll
  for (int step = 0; step < KSTEPS; ++step) {
    const int kb = czw * KSTEPS + step;
    const bf16x8 af = *(const bf16x8*)(arow + (size_t)kb * 32);
    const short* bp = Bs + (size_t)kb * 5120 + ln * 32 + quad * 8;
#pragma unroll
    for (int nt = 0; nt < 10; ++nt) {
      const bf16x8 bf = *(const bf16x8*)(bp + nt * 512);
      acc[nt] = __builtin_amdgcn_mfma_f32_16x16x32_bf16(af, bf, acc[nt], 0, 0, 0);
    }
  }
  // wave partials -> LDS (C layout: row=quad*4+r, col=nt*16+ln)
#pragma unroll
  for (int nt = 0; nt < 10; ++nt)
#pragma unroll
    for (int r = 0; r < 4; ++r)
      sbuf[wave][quad * 4 + r][nt * 16 + ln] = acc[nt][r];
  __syncthreads();
  // block partial = sum of 4 waves; coalesced agent write-through stores
#pragma unroll
  for (int j = 0; j < 10; ++j) {
    const int e = tid + j * 256;  // 0..2559
    const int row = e / 160, col = e % 160;
    const float v = sbuf[0][row][col] + sbuf[1][row][col] +
                    sbuf[2][row][col] + sbuf[3][row][col];
    __hip_atomic_store(&s_part[((size_t)cz * B + m0 + row) * 160 + col], v,
                       __ATOMIC_RELAXED, __HIP_MEMORY_SCOPE_AGENT);
  }
  asm volatile("s_waitcnt vmcnt(0)" ::: "memory");  // stores at coherence point
  __syncthreads();
  if (tid == 0)
    flag = (__hip_atomic_fetch_add(&ctrS[mb], 1, __ATOMIC_RELAXED,
                                   __HIP_MEMORY_SCOPE_AGENT) == NCS - 1) ? 1 : 0;
  __syncthreads();
  if (!flag) return;
  if (tid == 0)
    __hip_atomic_store(&ctrS[mb], 0, __ATOMIC_RELAXED, __HIP_MEMORY_SCOPE_AGENT);
  if (tid < OD) einv[tid] = 1.f / esum_in[tid];  // prev-dispatch data
  __syncthreads();
  // finisher: 16 rows x 160 cols = 1280 u64 slots, 5 per thread; 8-lane
  // groups cover one (row, o) 16-col span -> width-8 shfl squash.
#pragma unroll
  for (int j = 0; j < 5; ++j) {
    const int e2 = tid + j * 256;         // 0..1279
    const int row = e2 / 80, c2p = e2 - row * 80;
    const int o = c2p >> 3;
    float sx = 0.f, sy = 0.f;
#pragma unroll
    for (int c2 = 0; c2 < NCS; ++c2) {
      const unsigned long long v = __hip_atomic_load(
          (const unsigned long long*)(s_part +
              ((size_t)c2 * B + m0 + row) * 160 + c2p * 2),
          __ATOMIC_RELAXED, __HIP_MEMORY_SCOPE_AGENT);
      union { unsigned long long u; float f[2]; } cv;
      cv.u = v;
      sx += cv.f[0]; sy += cv.f[1];
    }
    const float ei = einv[o];
    sx *= ei; sy *= ei;
    float sq = sx * sx + sy * sy;
    sq += __shfl_xor(sq, 1, 8);
    sq += __shfl_xor(sq, 2, 8);
    sq += __shfl_xor(sq, 4, 8);
    const float norm = sqrtf(sq + 1e-8f);
    const float scale = sq / ((1.f + sq) * norm);
    const int b = m0 + row, col = c2p * 2;
    if (write_out) {
      float2 val;
      val.x = sx * scale; val.y = sy * scale;
      *(float2*)(out + (size_t)b * 160 + col) = val;
    } else {
      short* vb = vB + ((size_t)(b >> 5) * 160 + col) * 32 + (b & 31);
      vb[0] = f2bf(sx * scale);
      vb[32] = f2bf(sy * scale);
    }
  }
}

// ---------------- agg2: bijT += agreement; finisher: Bs slice + esum --------
// grid (144 ig8, 4 kq). G[m=(i8q),(n=o*16+p)] = sum_b xT[iq][b]*v[b][op].
__global__ __launch_bounds__(256) void agg2_kernel(const short* __restrict__ xT,
                                                   const float* __restrict__ W,
                                                   const short* __restrict__ vB,
                                                   float* __restrict__ bijT,
                                                   short* __restrict__ Bs,
                                                   int* __restrict__ ctrA,
                                                   float* __restrict__ esumOut) {
  const int tid = threadIdx.x;
  const int ig8 = blockIdx.x, kq = blockIdx.y;
  const int mt = tid >> 6, lane = tid & 63;
  const int ln = lane & 15, quad = lane >> 4;
  f32x4 acc[10] = {};
  const short* arow = xT + (size_t)(ig8 * 64 + mt * 16 + ln) * B + kq * 128 + quad * 8;
#pragma unroll
  for (int kb = 0; kb < 4; ++kb) {
    const bf16x8 af = *(const bf16x8*)(arow + kb * 32);
    const short* bp = vB + ((size_t)(kq * 4 + kb) * 160 + ln) * 32 + quad * 8;
#pragma unroll
    for (int nt = 0; nt < 10; ++nt) {
      const bf16x8 bf = *(const bf16x8*)(bp + nt * 512);
      acc[nt] = __builtin_amdgcn_mfma_f32_16x16x32_bf16(af, bf, acc[nt], 0, 0, 0);
    }
  }
  // epilogue: contract G with W -> agreement; RETURNED atomics (ordering!)
  const int i = ig8 * 8 + mt * 2 + (quad >> 1);
  const int qb = (quad & 1) * 4;
  float rsum = 0.f;
#pragma unroll
  for (int nt = 0; nt < 10; ++nt) {
    const float4 wv = *(const float4*)(W + (((size_t)i * OD + nt) * PD + ln) * QD + qb);
    float pa = acc[nt][0] * wv.x + acc[nt][1] * wv.y + acc[nt][2] * wv.z + acc[nt][3] * wv.w;
    pa += __shfl_xor(pa, 1); pa += __shfl_xor(pa, 2); pa += __shfl_xor(pa, 4);
    pa += __shfl_xor(pa, 8); pa += __shfl_xor(pa, 16);
    if ((lane & 31) == 0)
      rsum += atomicAdd(&bijT[(size_t)nt * IC + i], pa * (1.0f / (float)B));
  }
  asm volatile("" :: "v"(rsum));
  __syncthreads();
  __shared__ int flag;
  __shared__ float eL[8][OD];
  if (tid == 0)
    flag = (__hip_atomic_fetch_add(&ctrA[ig8], 1, __ATOMIC_RELAXED,
                                   __HIP_MEMORY_SCOPE_AGENT) == NCB - 1) ? 1 : 0;
  __syncthreads();
  if (!flag) return;
  // finisher: rebuild Bs k-blocks [ig8*2, ig8*2+1] = exp(bij)*W (unnormalized)
  if (tid < 8 * OD) {
    const int il = tid / OD, o = tid - il * OD;
    const float bv = __hip_atomic_load(&bijT[(size_t)o * IC + ig8 * 8 + il],
                                       __ATOMIC_RELAXED, __HIP_MEMORY_SCOPE_AGENT);
    eL[il][o] = __expf(bv);
  }
  if (tid == 0)
    __hip_atomic_store(&ctrA[ig8], 0, __ATOMIC_RELAXED, __HIP_MEMORY_SCOPE_AGENT);
  __syncthreads();
  if (tid < OD) {  // softmax denominator contribution for this ig8's 8 i's
    float s = 0.f;
#pragma unroll
    for (int il = 0; il < 8; ++il) s += eL[il][tid];
    atomicAdd(&esumOut[tid], s);
  }
  for (int vb = tid; vb < 320; vb += 256) {
    const int kbl = vb / 160, n = vb - kbl * 160;
    const int kb = ig8 * 2 + kbl;
    const int o = n >> 4, pp = n & 15;
    short ov[32];
#pragma unroll
    for (int q4 = 0; q4 < 4; ++q4) {
      const int ii = kb * 4 + q4;
      const float ci = eL[ii - ig8 * 8][o];
      const float4* wp = (const float4*)(W + (((size_t)ii * OD + o) * PD + pp) * QD);
      const float4 w0 = wp[0], w1 = wp[1];
      ov[q4 * 8 + 0] = f2bf(ci * w0.x); ov[q4 * 8 + 1] = f2bf(ci * w0.y);
      ov[q4 * 8 + 2] = f2bf(ci * w0.z); ov[q4 * 8 + 3] = f2bf(ci * w0.w);
      ov[q4 * 8 + 4] = f2bf(ci * w1.x); ov[q4 * 8 + 5] = f2bf(ci * w1.y);
      ov[q4 * 8 + 6] = f2bf(ci * w1.z); ov[q4 * 8 + 7] = f2bf(ci * w1.w);
    }
    int4* dst = (int4*)(Bs + (size_t)(kb * 160 + n) * 32);
    const int4* src = (const int4*)ov;
#pragma unroll
    for (int j = 0; j < 4; ++j) dst[j] = src[j];
  }
}

// ---------------- launch: 12 dispatches (everything doubled/shadowed) -------

extern "C" void kernel_launch(void* const* d_in, const int* in_sizes, int n_in,
                              void* d_out, int out_size, void* d_ws, size_t ws_size,
                              hipStream_t stream) {
  const float* x = (const float*)d_in[0];  // [512,1152,8] fp32
  const float* W = (const float*)d_in[1];  // [1152,10,16,8] fp32
  float* out = (float*)d_out;              // [512,10,16] fp32

  // workspace ~28 MB; every buffer written before read per call
  float* bijT = (float*)d_ws;                          // 11520 f
  float* s_part = bijT + IO;                           // 12*512*160 f
  int* ctrS = (int*)(s_part + (size_t)NCS * B * 160);  // 32 i
  int* ctrA = ctrS + 32;                               // 160 i
  float* esum = (float*)(ctrA + 160);                  // 48 f (pad 64)
  short* vB = (short*)(esum + 64);                     // 16*160*32 shorts
  short* Bs = vB + (size_t)16 * 160 * 32;              // 288*160*32 shorts
  short* xB = Bs + (size_t)NKB * 160 * 32;             // 512*9216 shorts
  short* xT = xB + (size_t)B * KD;                     // 9216*512 shorts
  // shadow scratch (written by shadow agg2, never read by the real chain)
  float* bijT2 = (float*)(xT + (size_t)KD * B);        // 11520 f (poisoned ok)
  float* esum2 = bijT2 + IO;                           // 16 f (pad 64)
  short* Bs2 = (short*)(esum2 + 64);                   // 288*160*32 shorts

  const dim3 agrid(144, NCB);

  prep_kernel<<<TPX + 180, 256, 0, stream>>>(x, W, bijT, ctrS, ctrA, esum,
                                             Bs, xB, xT);
  prep_kernel<<<TPX + 180, 256, 0, stream>>>(x, W, bijT, ctrS, ctrA, esum,
                                             Bs, xB, xT);
  // iter 1 (esum slot0 pre-set to IC by prep) — sgemm doubled (idempotent)
  sgemm_kernel<<<MB * NCS, 256, 0, stream>>>(xB, Bs, esum, s_part, ctrS, vB, out, 0);
  sgemm_kernel<<<MB * NCS, 256, 0, stream>>>(xB, Bs, esum, s_part, ctrS, vB, out, 0);
  agg2_kernel<<<agrid, 256, 0, stream>>>(xT, W, vB, bijT, Bs, ctrA, esum + 16);
  agg2_kernel<<<agrid, 256, 0, stream>>>(xT, W, vB, bijT2, Bs2, ctrA, esum2);  // shadow
  // iter 2
  sgemm_kernel<<<MB * NCS, 256, 0, stream>>>(xB, Bs, esum + 16, s_part, ctrS, vB, out, 0);
  sgemm_kernel<<<MB * NCS, 256, 0, stream>>>(xB, Bs, esum + 16, s_part, ctrS, vB, out, 0);
  agg2_kernel<<<agrid, 256, 0, stream>>>(xT, W, vB, bijT, Bs, ctrA, esum + 32);
  agg2_kernel<<<agrid, 256, 0, stream>>>(xT, W, vB, bijT2, Bs2, ctrA, esum2);  // shadow
  // iter 3
  sgemm_kernel<<<MB * NCS, 256, 0, stream>>>(xB, Bs, esum + 32, s_part, ctrS, vB, out, 1);
  sgemm_kernel<<<MB * NCS, 256, 0, stream>>>(xB, Bs, esum + 32, s_part, ctrS, vB, out, 1);
}

// Round 16
// 176.410 us; speedup vs baseline: 1.5818x; 1.5818x over previous
//
#include <hip/hip_runtime.h>
#include <hip/hip_bf16.h>

// DigitCaps dynamic routing. Output fp32.
// R29: informed polish. R27/R28 diagnostics closed the model:
//   dur_us = C0(64.6 fixed: ~45us workspace re-poison fill + launch) +
//            3(S+b)(57.5) + (P+b)(~18) + 2(A+b)(~32)
// Kernels are latency/ramp-bound (2-4x traffic floors). Two fixes:
//  1. sgemm NCS 12->24 (KSTEPS 3, grid 768 = 3 blocks/CU, LDS 129/160KB):
//     2x TLP to hide K-loop L2 latency; finisher sums 24 partials.
//  2. agg2: fire-and-forget bijT atomics + s_waitcnt vmcnt(0) drain
//     (replaces 10-deep serialized returned-atomic chain; same release
//     mechanism as the 6-round-verified sgemm WT protocol).
// Chain: prep | sgemm | agg2 | sgemm | agg2 | sgemm  (6 dispatches).
#define B 512
#define IC 1152
#define QD 8
#define OD 10
#define PD 16
#define KD (IC * QD)       // 9216
#define NKB (KD / 32)      // 288 K32 blocks
#define NCS 24             // K-chunks for s GEMM; grid 32*24 = 768 blocks
#define KSTEPS 3           // 288 / (NCS*4 waves)
#define MB 32              // M-tiles (16 rows each)
#define NCB 4              // b-chunks for agreement GEMM (128 each)
#define SOP (B * OD * PD)  // 81920
#define IO (IC * OD)       // 11520
#define TPX ((B / 64) * (KD / 64))  // 8*144 = 1152 transpose tiles

typedef short bf16x8 __attribute__((ext_vector_type(8)));
typedef short bf16x4 __attribute__((ext_vector_type(4)));
typedef float f32x4 __attribute__((ext_vector_type(4)));

__device__ __forceinline__ short f2bf(float f) {
  union { float f; unsigned u; } x;
  x.f = f;
  unsigned r = x.u + 0x7FFFu + ((x.u >> 16) & 1u);  // RNE to bf16
  return (short)(r >> 16);
}

// ---------------- prep: xB + xT transpose, Bs = bf16(W), zero state ---------
__global__ __launch_bounds__(256) void prep_kernel(const float* __restrict__ x,
                                                   const float* __restrict__ W,
                                                   float* __restrict__ bijT,
                                                   int* __restrict__ ctrS,
                                                   int* __restrict__ ctrA,
                                                   float* __restrict__ esum,
                                                   short* __restrict__ Bs,
                                                   short* __restrict__ xB,
                                                   short* __restrict__ xT) {
  const int bid = blockIdx.x, tid = threadIdx.x;
  // distributed state zeroing
  {
    const int g = bid * 256 + tid;
    if (g < IO) bijT[g] = 0.f;
    const int z = g - IO;
    if (z >= 0) {
      if (z < 32) ctrS[z] = 0;
      else if (z < 192) ctrA[z - 32] = 0;
      else if (z < 240) esum[z - 192] = (z - 192 < 16) ? (float)IC : 0.f;
    }
  }
  if (bid < TPX) {
    // 64 b x 64 iq tile: read x fp32, emit xB (linear bf16) + xT (transposed)
    __shared__ short lds[64 * 72];  // [iq_loc][b_loc], pad 72
    const int bt = bid / (KD / 64), qt = bid % (KD / 64);
    const int b0 = bt * 64, c0 = qt * 64;
    const int row0 = tid >> 4, col4 = (tid & 15) * 4;
#pragma unroll
    for (int j = 0; j < 4; ++j) {
      const int row = row0 + j * 16;
      const float4 v = *(const float4*)(x + (size_t)(b0 + row) * KD + c0 + col4);
      bf16x4 ov;
      ov[0] = f2bf(v.x); ov[1] = f2bf(v.y); ov[2] = f2bf(v.z); ov[3] = f2bf(v.w);
      *(bf16x4*)(xB + (size_t)(b0 + row) * KD + c0 + col4) = ov;
      lds[(col4 + 0) * 72 + row] = ov[0];
      lds[(col4 + 1) * 72 + row] = ov[1];
      lds[(col4 + 2) * 72 + row] = ov[2];
      lds[(col4 + 3) * 72 + row] = ov[3];
    }
    __syncthreads();
    const int iq = tid & 63, seg = tid >> 6;  // 16 b per (iq,seg)
    const short* src = lds + iq * 72 + seg * 16;
    short* dst = xT + (size_t)(c0 + iq) * B + b0 + seg * 16;
    *(bf16x8*)dst = *(const bf16x8*)src;
    *(bf16x8*)(dst + 8) = *(const bf16x8*)(src + 8);
    return;
  }
  const int t = (bid - TPX) * 256 + tid;  // 0..46079
  const int kb = t / 160, n = t % 160;
  const int o = n >> 4, p = n & 15;
  short ov[32];
#pragma unroll
  for (int quad = 0; quad < 4; ++quad) {
    const int i = kb * 4 + quad;
    const float4* wp = (const float4*)(W + (((size_t)i * OD + o) * PD + p) * QD);
    const float4 w0 = wp[0], w1 = wp[1];
    ov[quad * 8 + 0] = f2bf(w0.x); ov[quad * 8 + 1] = f2bf(w0.y);
    ov[quad * 8 + 2] = f2bf(w0.z); ov[quad * 8 + 3] = f2bf(w0.w);
    ov[quad * 8 + 4] = f2bf(w1.x); ov[quad * 8 + 5] = f2bf(w1.y);
    ov[quad * 8 + 6] = f2bf(w1.z); ov[quad * 8 + 7] = f2bf(w1.w);
  }
  int4* dst = (int4*)(Bs + (size_t)t * 32);
  const int4* src = (const int4*)ov;
#pragma unroll
  for (int j = 0; j < 4; ++j) dst[j] = src[j];
}

// ---------------- sgemm: 16-row tile, 4-wave K-split, coalesced WT stores ---
// grid MB*NCS; mb = bid&31 (co-XCD per mb), cz = bid>>5. Finisher = last cz.
__global__ __launch_bounds__(256) void sgemm_kernel(const short* __restrict__ xB,
                                                    const short* __restrict__ Bs,
                                                    const float* __restrict__ esum_in,
                                                    float* __restrict__ s_part,
                                                    int* __restrict__ ctrS,
                                                    short* __restrict__ vB,
                                                    float* __restrict__ out,
                                                    int write_out) {
  __shared__ float sbuf[4][16][168];  // 43KB, +8 pad
  __shared__ int flag;
  __shared__ float einv[OD];
  const int tid = threadIdx.x;
  const int wave = tid >> 6, lane = tid & 63;
  const int ln = lane & 15, quad = lane >> 4;
  const int mb = blockIdx.x & 31, cz = blockIdx.x >> 5;  // co-XCD swizzle
  const int m0 = mb * 16;
  const int czw = cz * 4 + wave;  // 0..95 K-chunks of 3 K32-steps
  f32x4 acc[10] = {};
  const short* arow = xB + (size_t)(m0 + ln) * KD + quad * 8;
#pragma unroll
  for (int step = 0; step < KSTEPS; ++step) {
    const int kb = czw * KSTEPS + step;
    const bf16x8 af = *(const bf16x8*)(arow + (size_t)kb * 32);
    const short* bp = Bs + (size_t)kb * 5120 + ln * 32 + quad * 8;
#pragma unroll
    for (int nt = 0; nt < 10; ++nt) {
      const bf16x8 bf = *(const bf16x8*)(bp + nt * 512);
      acc[nt] = __builtin_amdgcn_mfma_f32_16x16x32_bf16(af, bf, acc[nt], 0, 0, 0);
    }
  }
  // wave partials -> LDS (C layout: row=quad*4+r, col=nt*16+ln)
#pragma unroll
  for (int nt = 0; nt < 10; ++nt)
#pragma unroll
    for (int r = 0; r < 4; ++r)
      sbuf[wave][quad * 4 + r][nt * 16 + ln] = acc[nt][r];
  __syncthreads();
  // block partial = sum of 4 waves; coalesced agent write-through stores
#pragma unroll
  for (int j = 0; j < 10; ++j) {
    const int e = tid + j * 256;  // 0..2559
    const int row = e / 160, col = e % 160;
    const float v = sbuf[0][row][col] + sbuf[1][row][col] +
                    sbuf[2][row][col] + sbuf[3][row][col];
    __hip_atomic_store(&s_part[((size_t)cz * B + m0 + row) * 160 + col], v,
                       __ATOMIC_RELAXED, __HIP_MEMORY_SCOPE_AGENT);
  }
  asm volatile("s_waitcnt vmcnt(0)" ::: "memory");  // stores at coherence point
  __syncthreads();
  if (tid == 0)
    flag = (__hip_atomic_fetch_add(&ctrS[mb], 1, __ATOMIC_RELAXED,
                                   __HIP_MEMORY_SCOPE_AGENT) == NCS - 1) ? 1 : 0;
  __syncthreads();
  if (!flag) return;
  if (tid == 0)
    __hip_atomic_store(&ctrS[mb], 0, __ATOMIC_RELAXED, __HIP_MEMORY_SCOPE_AGENT);
  if (tid < OD) einv[tid] = 1.f / esum_in[tid];  // prev-dispatch data
  __syncthreads();
  // finisher: 16 rows x 160 cols = 1280 u64 slots, 5 per thread; 8-lane
  // groups cover one (row, o) 16-col span -> width-8 shfl squash.
#pragma unroll
  for (int j = 0; j < 5; ++j) {
    const int e2 = tid + j * 256;         // 0..1279
    const int row = e2 / 80, c2p = e2 - row * 80;
    const int o = c2p >> 3;
    float sx = 0.f, sy = 0.f;
#pragma unroll
    for (int c2 = 0; c2 < NCS; ++c2) {
      const unsigned long long v = __hip_atomic_load(
          (const unsigned long long*)(s_part +
              ((size_t)c2 * B + m0 + row) * 160 + c2p * 2),
          __ATOMIC_RELAXED, __HIP_MEMORY_SCOPE_AGENT);
      union { unsigned long long u; float f[2]; } cv;
      cv.u = v;
      sx += cv.f[0]; sy += cv.f[1];
    }
    const float ei = einv[o];
    sx *= ei; sy *= ei;
    float sq = sx * sx + sy * sy;
    sq += __shfl_xor(sq, 1, 8);
    sq += __shfl_xor(sq, 2, 8);
    sq += __shfl_xor(sq, 4, 8);
    const float norm = sqrtf(sq + 1e-8f);
    const float scale = sq / ((1.f + sq) * norm);
    const int b = m0 + row, col = c2p * 2;
    if (write_out) {
      float2 val;
      val.x = sx * scale; val.y = sy * scale;
      *(float2*)(out + (size_t)b * 160 + col) = val;
    } else {
      short* vb = vB + ((size_t)(b >> 5) * 160 + col) * 32 + (b & 31);
      vb[0] = f2bf(sx * scale);
      vb[32] = f2bf(sy * scale);
    }
  }
}

// ---------------- agg2: bijT += agreement; finisher: Bs slice + esum --------
// grid (144 ig8, 4 kq). G[m=(i8q),(n=o*16+p)] = sum_b xT[iq][b]*v[b][op].
__global__ __launch_bounds__(256) void agg2_kernel(const short* __restrict__ xT,
                                                   const float* __restrict__ W,
                                                   const short* __restrict__ vB,
                                                   float* __restrict__ bijT,
                                                   short* __restrict__ Bs,
                                                   int* __restrict__ ctrA,
                                                   float* __restrict__ esumOut) {
  const int tid = threadIdx.x;
  const int ig8 = blockIdx.x, kq = blockIdx.y;
  const int mt = tid >> 6, lane = tid & 63;
  const int ln = lane & 15, quad = lane >> 4;
  f32x4 acc[10] = {};
  const short* arow = xT + (size_t)(ig8 * 64 + mt * 16 + ln) * B + kq * 128 + quad * 8;
#pragma unroll
  for (int kb = 0; kb < 4; ++kb) {
    const bf16x8 af = *(const bf16x8*)(arow + kb * 32);
    const short* bp = vB + ((size_t)(kq * 4 + kb) * 160 + ln) * 32 + quad * 8;
#pragma unroll
    for (int nt = 0; nt < 10; ++nt) {
      const bf16x8 bf = *(const bf16x8*)(bp + nt * 512);
      acc[nt] = __builtin_amdgcn_mfma_f32_16x16x32_bf16(af, bf, acc[nt], 0, 0, 0);
    }
  }
  // epilogue: contract G with W -> agreement; fire-and-forget atomics,
  // ordered by vmcnt(0) drain before the ctr bump (same release mechanism
  // as the sgemm WT protocol).
  const int i = ig8 * 8 + mt * 2 + (quad >> 1);
  const int qb = (quad & 1) * 4;
#pragma unroll
  for (int nt = 0; nt < 10; ++nt) {
    const float4 wv = *(const float4*)(W + (((size_t)i * OD + nt) * PD + ln) * QD + qb);
    float pa = acc[nt][0] * wv.x + acc[nt][1] * wv.y + acc[nt][2] * wv.z + acc[nt][3] * wv.w;
    pa += __shfl_xor(pa, 1); pa += __shfl_xor(pa, 2); pa += __shfl_xor(pa, 4);
    pa += __shfl_xor(pa, 8); pa += __shfl_xor(pa, 16);
    if ((lane & 31) == 0)
      atomicAdd(&bijT[(size_t)nt * IC + i], pa * (1.0f / (float)B));
  }
  asm volatile("s_waitcnt vmcnt(0)" ::: "memory");  // atomics at coherence point
  __syncthreads();
  __shared__ int flag;
  __shared__ float eL[8][OD];
  if (tid == 0)
    flag = (__hip_atomic_fetch_add(&ctrA[ig8], 1, __ATOMIC_RELAXED,
                                   __HIP_MEMORY_SCOPE_AGENT) == NCB - 1) ? 1 : 0;
  __syncthreads();
  if (!flag) return;
  // finisher: rebuild Bs k-blocks [ig8*2, ig8*2+1] = exp(bij)*W (unnormalized)
  if (tid < 8 * OD) {
    const int il = tid / OD, o = tid - il * OD;
    const float bv = __hip_atomic_load(&bijT[(size_t)o * IC + ig8 * 8 + il],
                                       __ATOMIC_RELAXED, __HIP_MEMORY_SCOPE_AGENT);
    eL[il][o] = __expf(bv);
  }
  if (tid == 0)
    __hip_atomic_store(&ctrA[ig8], 0, __ATOMIC_RELAXED, __HIP_MEMORY_SCOPE_AGENT);
  __syncthreads();
  if (tid < OD) {  // softmax denominator contribution for this ig8's 8 i's
    float s = 0.f;
#pragma unroll
    for (int il = 0; il < 8; ++il) s += eL[il][tid];
    atomicAdd(&esumOut[tid], s);
  }
  for (int vb = tid; vb < 320; vb += 256) {
    const int kbl = vb / 160, n = vb - kbl * 160;
    const int kb = ig8 * 2 + kbl;
    const int o = n >> 4, pp = n & 15;
    short ov[32];
#pragma unroll
    for (int q4 = 0; q4 < 4; ++q4) {
      const int ii = kb * 4 + q4;
      const float ci = eL[ii - ig8 * 8][o];
      const float4* wp = (const float4*)(W + (((size_t)ii * OD + o) * PD + pp) * QD);
      const float4 w0 = wp[0], w1 = wp[1];
      ov[q4 * 8 + 0] = f2bf(ci * w0.x); ov[q4 * 8 + 1] = f2bf(ci * w0.y);
      ov[q4 * 8 + 2] = f2bf(ci * w0.z); ov[q4 * 8 + 3] = f2bf(ci * w0.w);
      ov[q4 * 8 + 4] = f2bf(ci * w1.x); ov[q4 * 8 + 5] = f2bf(ci * w1.y);
      ov[q4 * 8 + 6] = f2bf(ci * w1.z); ov[q4 * 8 + 7] = f2bf(ci * w1.w);
    }
    int4* dst = (int4*)(Bs + (size_t)(kb * 160 + n) * 32);
    const int4* src = (const int4*)ov;
#pragma unroll
    for (int j = 0; j < 4; ++j) dst[j] = src[j];
  }
}

// ---------------- launch: 6 dispatches --------------------------------------

extern "C" void kernel_launch(void* const* d_in, const int* in_sizes, int n_in,
                              void* d_out, int out_size, void* d_ws, size_t ws_size,
                              hipStream_t stream) {
  const float* x = (const float*)d_in[0];  // [512,1152,8] fp32
  const float* W = (const float*)d_in[1];  // [1152,10,16,8] fp32
  float* out = (float*)d_out;              // [512,10,16] fp32

  // workspace ~29 MB; every buffer written before read per call
  float* bijT = (float*)d_ws;                          // 11520 f
  float* s_part = bijT + IO;                           // 24*512*160 f
  int* ctrS = (int*)(s_part + (size_t)NCS * B * 160);  // 32 i
  int* ctrA = ctrS + 32;                               // 160 i
  float* esum = (float*)(ctrA + 160);                  // 48 f (pad 64)
  short* vB = (short*)(esum + 64);                     // 16*160*32 shorts
  short* Bs = vB + (size_t)16 * 160 * 32;              // 288*160*32 shorts
  short* xB = Bs + (size_t)NKB * 160 * 32;             // 512*9216 shorts
  short* xT = xB + (size_t)B * KD;                     // 9216*512 shorts

  const dim3 agrid(144, NCB);

  prep_kernel<<<TPX + 180, 256, 0, stream>>>(x, W, bijT, ctrS, ctrA, esum,
                                             Bs, xB, xT);
  // iter 1 (esum slot0 pre-set to IC by prep)
  sgemm_kernel<<<MB * NCS, 256, 0, stream>>>(xB, Bs, esum, s_part, ctrS, vB, out, 0);
  agg2_kernel<<<agrid, 256, 0, stream>>>(xT, W, vB, bijT, Bs, ctrA, esum + 16);
  // iter 2
  sgemm_kernel<<<MB * NCS, 256, 0, stream>>>(xB, Bs, esum + 16, s_part, ctrS, vB, out, 0);
  agg2_kernel<<<agrid, 256, 0, stream>>>(xT, W, vB, bijT, Bs, ctrA, esum + 32);
  // iter 3
  sgemm_kernel<<<MB * NCS, 256, 0, stream>>>(xB, Bs, esum + 32, s_part, ctrS, vB, out, 1);
}

// Round 17
// 172.600 us; speedup vs baseline: 1.6167x; 1.0221x over previous
//
#include <hip/hip_runtime.h>
#include <hip/hip_bf16.h>

// DigitCaps dynamic routing. Output fp32.
// R31 = R26 champion restored verbatim (171.8us). R29's two "informed"
// shaves both regressed (176.4): NCS=24 doubled the finisher dependency
// tail; agg2 drain change was noise. Model (closed by R27/R28 diagnostics):
//   dur = C0(~65 fixed harness fill+launch) + 3(S+b)(57.5) + (P+b)(~18)
//         + 2(A+b)(~32); kernels latency/tail-bound at 2-3x traffic floors.
// Structure: R20 WT-store/ctr/finisher protocol + co-XCD swizzle + u64
// bypass finisher loads. Chain: prep | sgemm | agg2 | x2 | sgemm.
#define B 512
#define IC 1152
#define QD 8
#define OD 10
#define PD 16
#define KD (IC * QD)       // 9216
#define NKB (KD / 32)      // 288 K32 blocks
#define NCS 12             // K-chunks for s GEMM; grid 32*12 = 384 blocks
#define KSTEPS 6           // 288 / (NCS*4 waves)
#define MB 32              // M-tiles (16 rows each)
#define NCB 4              // b-chunks for agreement GEMM (128 each)
#define SOP (B * OD * PD)  // 81920
#define IO (IC * OD)       // 11520
#define TPX ((B / 64) * (KD / 64))  // 8*144 = 1152 transpose tiles

typedef short bf16x8 __attribute__((ext_vector_type(8)));
typedef short bf16x4 __attribute__((ext_vector_type(4)));
typedef float f32x4 __attribute__((ext_vector_type(4)));

__device__ __forceinline__ short f2bf(float f) {
  union { float f; unsigned u; } x;
  x.f = f;
  unsigned r = x.u + 0x7FFFu + ((x.u >> 16) & 1u);  // RNE to bf16
  return (short)(r >> 16);
}

// ---------------- prep: xB + xT transpose, Bs = bf16(W), zero state ---------
__global__ __launch_bounds__(256) void prep_kernel(const float* __restrict__ x,
                                                   const float* __restrict__ W,
                                                   float* __restrict__ bijT,
                                                   int* __restrict__ ctrS,
                                                   int* __restrict__ ctrA,
                                                   float* __restrict__ esum,
                                                   short* __restrict__ Bs,
                                                   short* __restrict__ xB,
                                                   short* __restrict__ xT) {
  const int bid = blockIdx.x, tid = threadIdx.x;
  // distributed state zeroing
  {
    const int g = bid * 256 + tid;
    if (g < IO) bijT[g] = 0.f;
    const int z = g - IO;
    if (z >= 0) {
      if (z < 32) ctrS[z] = 0;
      else if (z < 192) ctrA[z - 32] = 0;
      else if (z < 240) esum[z - 192] = (z - 192 < 16) ? (float)IC : 0.f;
    }
  }
  if (bid < TPX) {
    // 64 b x 64 iq tile: read x fp32, emit xB (linear bf16) + xT (transposed)
    __shared__ short lds[64 * 72];  // [iq_loc][b_loc], pad 72
    const int bt = bid / (KD / 64), qt = bid % (KD / 64);
    const int b0 = bt * 64, c0 = qt * 64;
    const int row0 = tid >> 4, col4 = (tid & 15) * 4;
#pragma unroll
    for (int j = 0; j < 4; ++j) {
      const int row = row0 + j * 16;
      const float4 v = *(const float4*)(x + (size_t)(b0 + row) * KD + c0 + col4);
      bf16x4 ov;
      ov[0] = f2bf(v.x); ov[1] = f2bf(v.y); ov[2] = f2bf(v.z); ov[3] = f2bf(v.w);
      *(bf16x4*)(xB + (size_t)(b0 + row) * KD + c0 + col4) = ov;
      lds[(col4 + 0) * 72 + row] = ov[0];
      lds[(col4 + 1) * 72 + row] = ov[1];
      lds[(col4 + 2) * 72 + row] = ov[2];
      lds[(col4 + 3) * 72 + row] = ov[3];
    }
    __syncthreads();
    const int iq = tid & 63, seg = tid >> 6;  // 16 b per (iq,seg)
    const short* src = lds + iq * 72 + seg * 16;
    short* dst = xT + (size_t)(c0 + iq) * B + b0 + seg * 16;
    *(bf16x8*)dst = *(const bf16x8*)src;
    *(bf16x8*)(dst + 8) = *(const bf16x8*)(src + 8);
    return;
  }
  const int t = (bid - TPX) * 256 + tid;  // 0..46079
  const int kb = t / 160, n = t % 160;
  const int o = n >> 4, p = n & 15;
  short ov[32];
#pragma unroll
  for (int quad = 0; quad < 4; ++quad) {
    const int i = kb * 4 + quad;
    const float4* wp = (const float4*)(W + (((size_t)i * OD + o) * PD + p) * QD);
    const float4 w0 = wp[0], w1 = wp[1];
    ov[quad * 8 + 0] = f2bf(w0.x); ov[quad * 8 + 1] = f2bf(w0.y);
    ov[quad * 8 + 2] = f2bf(w0.z); ov[quad * 8 + 3] = f2bf(w0.w);
    ov[quad * 8 + 4] = f2bf(w1.x); ov[quad * 8 + 5] = f2bf(w1.y);
    ov[quad * 8 + 6] = f2bf(w1.z); ov[quad * 8 + 7] = f2bf(w1.w);
  }
  int4* dst = (int4*)(Bs + (size_t)t * 32);
  const int4* src = (const int4*)ov;
#pragma unroll
  for (int j = 0; j < 4; ++j) dst[j] = src[j];
}

// ---------------- sgemm: 16-row tile, 4-wave K-split, coalesced WT stores ---
// grid MB*NCS; mb = bid&31 (co-XCD per mb), cz = bid>>5. Finisher = last cz.
__global__ __launch_bounds__(256) void sgemm_kernel(const short* __restrict__ xB,
                                                    const short* __restrict__ Bs,
                                                    const float* __restrict__ esum_in,
                                                    float* __restrict__ s_part,
                                                    int* __restrict__ ctrS,
                                                    short* __restrict__ vB,
                                                    float* __restrict__ out,
                                                    int write_out) {
  __shared__ float sbuf[4][16][168];  // 43KB, +8 pad
  __shared__ int flag;
  __shared__ float einv[OD];
  const int tid = threadIdx.x;
  const int wave = tid >> 6, lane = tid & 63;
  const int ln = lane & 15, quad = lane >> 4;
  const int mb = blockIdx.x & 31, cz = blockIdx.x >> 5;  // co-XCD swizzle
  const int m0 = mb * 16;
  const int czw = cz * 4 + wave;  // 0..47 K-chunks of 6 K32-steps
  f32x4 acc[10] = {};
  const short* arow = xB + (size_t)(m0 + ln) * KD + quad * 8;
#pragma unroll
  for (int step = 0; step < KSTEPS; ++step) {
    const int kb = czw * KSTEPS + step;
    const bf16x8 af = *(const bf16x8*)(arow + (size_t)kb * 32);
    const short* bp = Bs + (size_t)kb * 5120 + ln * 32 + quad * 8;
#pragma unroll
    for (int nt = 0; nt < 10; ++nt) {
      const bf16x8 bf = *(const bf16x8*)(bp + nt * 512);
      acc[nt] = __builtin_amdgcn_mfma_f32_16x16x32_bf16(af, bf, acc[nt], 0, 0, 0);
    }
  }
  // wave partials -> LDS (C layout: row=quad*4+r, col=nt*16+ln)
#pragma unroll
  for (int nt = 0; nt < 10; ++nt)
#pragma unroll
    for (int r = 0; r < 4; ++r)
      sbuf[wave][quad * 4 + r][nt * 16 + ln] = acc[nt][r];
  __syncthreads();
  // block partial = sum of 4 waves; coalesced agent write-through stores
#pragma unroll
  for (int j = 0; j < 10; ++j) {
    const int e = tid + j * 256;  // 0..2559
    const int row = e / 160, col = e % 160;
    const float v = sbuf[0][row][col] + sbuf[1][row][col] +
                    sbuf[2][row][col] + sbuf[3][row][col];
    __hip_atomic_store(&s_part[((size_t)cz * B + m0 + row) * 160 + col], v,
                       __ATOMIC_RELAXED, __HIP_MEMORY_SCOPE_AGENT);
  }
  asm volatile("s_waitcnt vmcnt(0)" ::: "memory");  // stores at coherence point
  __syncthreads();
  if (tid == 0)
    flag = (__hip_atomic_fetch_add(&ctrS[mb], 1, __ATOMIC_RELAXED,
                                   __HIP_MEMORY_SCOPE_AGENT) == NCS - 1) ? 1 : 0;
  __syncthreads();
  if (!flag) return;
  if (tid == 0)
    __hip_atomic_store(&ctrS[mb], 0, __ATOMIC_RELAXED, __HIP_MEMORY_SCOPE_AGENT);
  if (tid < OD) einv[tid] = 1.f / esum_in[tid];  // prev-dispatch data
  __syncthreads();
  // finisher: 16 rows x 160 cols = 1280 u64 slots, 5 per thread; 8-lane
  // groups cover one (row, o) 16-col span -> width-8 shfl squash.
#pragma unroll
  for (int j = 0; j < 5; ++j) {
    const int e2 = tid + j * 256;         // 0..1279
    const int row = e2 / 80, c2p = e2 - row * 80;
    const int o = c2p >> 3;
    float sx = 0.f, sy = 0.f;
#pragma unroll
    for (int c2 = 0; c2 < NCS; ++c2) {
      const unsigned long long v = __hip_atomic_load(
          (const unsigned long long*)(s_part +
              ((size_t)c2 * B + m0 + row) * 160 + c2p * 2),
          __ATOMIC_RELAXED, __HIP_MEMORY_SCOPE_AGENT);
      union { unsigned long long u; float f[2]; } cv;
      cv.u = v;
      sx += cv.f[0]; sy += cv.f[1];
    }
    const float ei = einv[o];
    sx *= ei; sy *= ei;
    float sq = sx * sx + sy * sy;
    sq += __shfl_xor(sq, 1, 8);
    sq += __shfl_xor(sq, 2, 8);
    sq += __shfl_xor(sq, 4, 8);
    const float norm = sqrtf(sq + 1e-8f);
    const float scale = sq / ((1.f + sq) * norm);
    const int b = m0 + row, col = c2p * 2;
    if (write_out) {
      float2 val;
      val.x = sx * scale; val.y = sy * scale;
      *(float2*)(out + (size_t)b * 160 + col) = val;
    } else {
      short* vb = vB + ((size_t)(b >> 5) * 160 + col) * 32 + (b & 31);
      vb[0] = f2bf(sx * scale);
      vb[32] = f2bf(sy * scale);
    }
  }
}

// ---------------- agg2: bijT += agreement; finisher: Bs slice + esum --------
// grid (144 ig8, 4 kq). G[m=(i8q),(n=o*16+p)] = sum_b xT[iq][b]*v[b][op].
__global__ __launch_bounds__(256) void agg2_kernel(const short* __restrict__ xT,
                                                   const float* __restrict__ W,
                                                   const short* __restrict__ vB,
                                                   float* __restrict__ bijT,
                                                   short* __restrict__ Bs,
                                                   int* __restrict__ ctrA,
                                                   float* __restrict__ esumOut) {
  const int tid = threadIdx.x;
  const int ig8 = blockIdx.x, kq = blockIdx.y;
  const int mt = tid >> 6, lane = tid & 63;
  const int ln = lane & 15, quad = lane >> 4;
  f32x4 acc[10] = {};
  const short* arow = xT + (size_t)(ig8 * 64 + mt * 16 + ln) * B + kq * 128 + quad * 8;
#pragma unroll
  for (int kb = 0; kb < 4; ++kb) {
    const bf16x8 af = *(const bf16x8*)(arow + kb * 32);
    const short* bp = vB + ((size_t)(kq * 4 + kb) * 160 + ln) * 32 + quad * 8;
#pragma unroll
    for (int nt = 0; nt < 10; ++nt) {
      const bf16x8 bf = *(const bf16x8*)(bp + nt * 512);
      acc[nt] = __builtin_amdgcn_mfma_f32_16x16x32_bf16(af, bf, acc[nt], 0, 0, 0);
    }
  }
  // epilogue: contract G with W -> agreement; RETURNED atomics (ordering!)
  const int i = ig8 * 8 + mt * 2 + (quad >> 1);
  const int qb = (quad & 1) * 4;
  float rsum = 0.f;
#pragma unroll
  for (int nt = 0; nt < 10; ++nt) {
    const float4 wv = *(const float4*)(W + (((size_t)i * OD + nt) * PD + ln) * QD + qb);
    float pa = acc[nt][0] * wv.x + acc[nt][1] * wv.y + acc[nt][2] * wv.z + acc[nt][3] * wv.w;
    pa += __shfl_xor(pa, 1); pa += __shfl_xor(pa, 2); pa += __shfl_xor(pa, 4);
    pa += __shfl_xor(pa, 8); pa += __shfl_xor(pa, 16);
    if ((lane & 31) == 0)
      rsum += atomicAdd(&bijT[(size_t)nt * IC + i], pa * (1.0f / (float)B));
  }
  asm volatile("" :: "v"(rsum));
  __syncthreads();
  __shared__ int flag;
  __shared__ float eL[8][OD];
  if (tid == 0)
    flag = (__hip_atomic_fetch_add(&ctrA[ig8], 1, __ATOMIC_RELAXED,
                                   __HIP_MEMORY_SCOPE_AGENT) == NCB - 1) ? 1 : 0;
  __syncthreads();
  if (!flag) return;
  // finisher: rebuild Bs k-blocks [ig8*2, ig8*2+1] = exp(bij)*W (unnormalized)
  if (tid < 8 * OD) {
    const int il = tid / OD, o = tid - il * OD;
    const float bv = __hip_atomic_load(&bijT[(size_t)o * IC + ig8 * 8 + il],
                                       __ATOMIC_RELAXED, __HIP_MEMORY_SCOPE_AGENT);
    eL[il][o] = __expf(bv);
  }
  if (tid == 0)
    __hip_atomic_store(&ctrA[ig8], 0, __ATOMIC_RELAXED, __HIP_MEMORY_SCOPE_AGENT);
  __syncthreads();
  if (tid < OD) {  // softmax denominator contribution for this ig8's 8 i's
    float s = 0.f;
#pragma unroll
    for (int il = 0; il < 8; ++il) s += eL[il][tid];
    atomicAdd(&esumOut[tid], s);
  }
  for (int vb = tid; vb < 320; vb += 256) {
    const int kbl = vb / 160, n = vb - kbl * 160;
    const int kb = ig8 * 2 + kbl;
    const int o = n >> 4, pp = n & 15;
    short ov[32];
#pragma unroll
    for (int q4 = 0; q4 < 4; ++q4) {
      const int ii = kb * 4 + q4;
      const float ci = eL[ii - ig8 * 8][o];
      const float4* wp = (const float4*)(W + (((size_t)ii * OD + o) * PD + pp) * QD);
      const float4 w0 = wp[0], w1 = wp[1];
      ov[q4 * 8 + 0] = f2bf(ci * w0.x); ov[q4 * 8 + 1] = f2bf(ci * w0.y);
      ov[q4 * 8 + 2] = f2bf(ci * w0.z); ov[q4 * 8 + 3] = f2bf(ci * w0.w);
      ov[q4 * 8 + 4] = f2bf(ci * w1.x); ov[q4 * 8 + 5] = f2bf(ci * w1.y);
      ov[q4 * 8 + 6] = f2bf(ci * w1.z); ov[q4 * 8 + 7] = f2bf(ci * w1.w);
    }
    int4* dst = (int4*)(Bs + (size_t)(kb * 160 + n) * 32);
    const int4* src = (const int4*)ov;
#pragma unroll
    for (int j = 0; j < 4; ++j) dst[j] = src[j];
  }
}

// ---------------- launch: 6 dispatches --------------------------------------

extern "C" void kernel_launch(void* const* d_in, const int* in_sizes, int n_in,
                              void* d_out, int out_size, void* d_ws, size_t ws_size,
                              hipStream_t stream) {
  const float* x = (const float*)d_in[0];  // [512,1152,8] fp32
  const float* W = (const float*)d_in[1];  // [1152,10,16,8] fp32
  float* out = (float*)d_out;              // [512,10,16] fp32

  // workspace ~25 MB; every buffer written before read per call
  float* bijT = (float*)d_ws;                          // 11520 f
  float* s_part = bijT + IO;                           // 12*512*160 f
  int* ctrS = (int*)(s_part + (size_t)NCS * B * 160);  // 32 i
  int* ctrA = ctrS + 32;                               // 160 i
  float* esum = (float*)(ctrA + 160);                  // 48 f (pad 64)
  short* vB = (short*)(esum + 64);                     // 16*160*32 shorts
  short* Bs = vB + (size_t)16 * 160 * 32;              // 288*160*32 shorts
  short* xB = Bs + (size_t)NKB * 160 * 32;             // 512*9216 shorts
  short* xT = xB + (size_t)B * KD;                     // 9216*512 shorts

  const dim3 agrid(144, NCB);

  prep_kernel<<<TPX + 180, 256, 0, stream>>>(x, W, bijT, ctrS, ctrA, esum,
                                             Bs, xB, xT);
  // iter 1 (esum slot0 pre-set to IC by prep)
  sgemm_kernel<<<MB * NCS, 256, 0, stream>>>(xB, Bs, esum, s_part, ctrS, vB, out, 0);
  agg2_kernel<<<agrid, 256, 0, stream>>>(xT, W, vB, bijT, Bs, ctrA, esum + 16);
  // iter 2
  sgemm_kernel<<<MB * NCS, 256, 0, stream>>>(xB, Bs, esum + 16, s_part, ctrS, vB, out, 0);
  agg2_kernel<<<agrid, 256, 0, stream>>>(xT, W, vB, bijT, Bs, ctrA, esum + 32);
  // iter 3
  sgemm_kernel<<<MB * NCS, 256, 0, stream>>>(xB, Bs, esum + 32, s_part, ctrS, vB, out, 1);
}